// Round 1
// baseline (1974.403 us; speedup 1.0000x reference)
//
#include <hip/hip_runtime.h>
#include <math.h>

// Problem constants (fixed by the reference)
#define N      4096          // N_HID == N_TH == N_TP
#define N8     (N / 8)       // 512 groups of 8 bf16 (one uint4) per row
#define KSTEPS 8
#define NF     16384         // feature length for W3 (nH + nP + 2*maxL)

// ---------------------------------------------------------------------------
// bf16 helpers: weights are stored as packed bf16 (2 per uint32), vectors and
// accumulation stay fp32.  bflo/bfhi unpack the low/high bf16 of a uint32.
// ---------------------------------------------------------------------------
__device__ __forceinline__ float bflo(uint32_t u) { return __uint_as_float(u << 16); }
__device__ __forceinline__ float bfhi(uint32_t u) { return __uint_as_float(u & 0xffff0000u); }
__device__ __forceinline__ uint32_t f2bf(float f) {
    // round-to-nearest-even fp32 -> bf16 (inputs are finite normals)
    uint32_t u = __float_as_uint(f);
    return (u + 0x7fffu + ((u >> 16) & 1u)) >> 16;
}
__device__ __forceinline__ float wave_reduce(float v) {
#pragma unroll
    for (int off = 32; off > 0; off >>= 1) v += __shfl_down(v, off, 64);
    return v;
}

// ---------------------------------------------------------------------------
// fp32 -> packed bf16 conversion, 8 elements (32B read, 16B write) per iter.
// ---------------------------------------------------------------------------
__global__ void convert_bf16_kernel(const float* __restrict__ src,
                                    uint4* __restrict__ dst, int n8) {
    int i = blockIdx.x * blockDim.x + threadIdx.x;
    int stride = gridDim.x * blockDim.x;
    const float4* s = (const float4*)src;
    for (; i < n8; i += stride) {
        float4 a = s[2 * (size_t)i];
        float4 b = s[2 * (size_t)i + 1];
        uint4 o;
        o.x = f2bf(a.x) | (f2bf(a.y) << 16);
        o.y = f2bf(a.z) | (f2bf(a.w) << 16);
        o.z = f2bf(b.x) | (f2bf(b.y) << 16);
        o.w = f2bf(b.z) | (f2bf(b.w) << 16);
        dst[i] = o;
    }
}

// ---------------------------------------------------------------------------
// fp32 weighted column sum (used only for the M_h init path):
// out[j] += sum_{i in slice} w[i] * M[i][j].  out must be pre-zeroed.
// ---------------------------------------------------------------------------
__global__ void colsum_kernel(const float* __restrict__ M,
                              const float* __restrict__ w,
                              float* __restrict__ out,
                              int rowsPerSlice) {
    int c4 = blockIdx.x * blockDim.x + threadIdx.x;      // float4 column idx
    int i0 = blockIdx.y * rowsPerSlice;
    float4 acc = make_float4(0.f, 0.f, 0.f, 0.f);
    for (int i = i0; i < i0 + rowsPerSlice; ++i) {
        float wi = w[i];
        float4 m = ((const float4*)(M + (size_t)i * N))[c4];
        acc.x += wi * m.x;
        acc.y += wi * m.y;
        acc.z += wi * m.z;
        acc.w += wi * m.w;
    }
    atomicAdd(&out[c4 * 4 + 0], acc.x);
    atomicAdd(&out[c4 * 4 + 1], acc.y);
    atomicAdd(&out[c4 * 4 + 2], acc.z);
    atomicAdd(&out[c4 * 4 + 3], acc.w);
}

// ---------------------------------------------------------------------------
// bf16 weighted column sum: out[j] += sum_{i in slice} w[i] * Mb[i][j].
// Each thread owns 8 consecutive columns (one uint4 = 8 bf16).
// grid = (2, 256), block = 256, rowsPerSlice = 16.
// ---------------------------------------------------------------------------
__global__ void colsum_bf16_kernel(const ushort* __restrict__ Mb,
                                   const float* __restrict__ w,
                                   float* __restrict__ out,
                                   int rowsPerSlice) {
    int c8 = blockIdx.x * blockDim.x + threadIdx.x;      // [0, 512)
    int i0 = blockIdx.y * rowsPerSlice;
    float a0 = 0.f, a1 = 0.f, a2 = 0.f, a3 = 0.f;
    float a4 = 0.f, a5 = 0.f, a6 = 0.f, a7 = 0.f;
    for (int i = i0; i < i0 + rowsPerSlice; ++i) {
        float wi = w[i];
        uint4 m = ((const uint4*)(Mb + (size_t)i * N))[c8];
        a0 += wi * bflo(m.x); a1 += wi * bfhi(m.x);
        a2 += wi * bflo(m.y); a3 += wi * bfhi(m.y);
        a4 += wi * bflo(m.z); a5 += wi * bfhi(m.z);
        a6 += wi * bflo(m.w); a7 += wi * bfhi(m.w);
    }
    float* o = out + c8 * 8;
    atomicAdd(o + 0, a0); atomicAdd(o + 1, a1);
    atomicAdd(o + 2, a2); atomicAdd(o + 3, a3);
    atomicAdd(o + 4, a4); atomicAdd(o + 5, a5);
    atomicAdd(o + 6, a6); atomicAdd(o + 7, a7);
}

// ---------------------------------------------------------------------------
// u[row] = dot(W2b[row, :], sk)  (bf16 weights, fp32 vector/accum).
// One block (256 thr) per row; wave-shuffle reduction.
// Also zeroes bufv[row] for the following colsum.
// ---------------------------------------------------------------------------
__global__ void rowdot_u_bf16_kernel(const ushort* __restrict__ W2b,
                                     const float* __restrict__ sk,
                                     float* __restrict__ u,
                                     float* __restrict__ bufv) {
    int row = blockIdx.x;
    const uint4* r = (const uint4*)(W2b + (size_t)row * N);
    const float4* x = (const float4*)sk;
    float acc = 0.f;
    for (int c = threadIdx.x; c < N8; c += blockDim.x) {
        uint4 a = r[c];
        float4 b0 = x[2 * c], b1 = x[2 * c + 1];
        acc += bflo(a.x) * b0.x + bfhi(a.x) * b0.y
             + bflo(a.y) * b0.z + bfhi(a.y) * b0.w
             + bflo(a.z) * b1.x + bfhi(a.z) * b1.y
             + bflo(a.w) * b1.z + bfhi(a.w) * b1.w;
    }
    acc = wave_reduce(acc);
    __shared__ float s4[4];
    if ((threadIdx.x & 63) == 0) s4[threadIdx.x >> 6] = acc;
    __syncthreads();
    if (threadIdx.x == 0) {
        u[row]    = s4[0] + s4[1] + s4[2] + s4[3];
        bufv[row] = 0.f;     // pre-zero logits buffer for the next colsum
    }
}

// ---------------------------------------------------------------------------
// Single-block softmax over N entries: wgt = softmax(v).
// Optionally zeroes zbuf[0..N) (the xk accumulator for the next colsum).
// ---------------------------------------------------------------------------
__global__ void softmax_kernel(const float* __restrict__ v,
                               float* __restrict__ wgt,
                               float* __restrict__ zbuf) {
    __shared__ float red[1024];
    int tid = threadIdx.x;
    float m = -1e30f;
    for (int i = tid; i < N; i += 1024) m = fmaxf(m, v[i]);
    red[tid] = m;
    __syncthreads();
    for (int s = 512; s > 0; s >>= 1) {
        if (tid < s) red[tid] = fmaxf(red[tid], red[tid + s]);
        __syncthreads();
    }
    float mx = red[0];
    __syncthreads();
    float sum = 0.f;
    for (int i = tid; i < N; i += 1024) {
        float e = expf(v[i] - mx);
        wgt[i] = e;
        sum += e;
    }
    red[tid] = sum;
    __syncthreads();
    for (int s = 512; s > 0; s >>= 1) {
        if (tid < s) red[tid] += red[tid + s];
        __syncthreads();
    }
    float inv = 1.f / red[0];
    for (int i = tid; i < N; i += 1024) wgt[i] *= inv;
    if (zbuf) {
        for (int i = tid; i < N; i += 1024) zbuf[i] = 0.f;
    }
}

// ---------------------------------------------------------------------------
// Fused GRU cell with bf16 weights: one block per hidden unit t.  Computes
// the 6 row-dots (i_r,i_z,i_n,h_r,h_z,h_n), applies gates, writes h_out[t].
// Blocks 0..2 also zero logits3 for the following feat reduction.
// ---------------------------------------------------------------------------
__global__ void gru_bf16_kernel(const ushort* __restrict__ wihb,
                                const ushort* __restrict__ whhb,
                                const float* __restrict__ xk,
                                const float* __restrict__ h,
                                float* __restrict__ h_out,
                                float* __restrict__ logits3) {
    int t = blockIdx.x;
    float acc[6] = {0.f, 0.f, 0.f, 0.f, 0.f, 0.f};
    const float4* xv = (const float4*)xk;
    const float4* hv = (const float4*)h;
#pragma unroll
    for (int g = 0; g < 3; ++g) {
        const uint4* wi = (const uint4*)(wihb + (size_t)(g * N + t) * N);
        const uint4* wh = (const uint4*)(whhb + (size_t)(g * N + t) * N);
        for (int c = threadIdx.x; c < N8; c += blockDim.x) {
            uint4 a = wi[c];
            float4 b0 = xv[2 * c], b1 = xv[2 * c + 1];
            acc[g] += bflo(a.x) * b0.x + bfhi(a.x) * b0.y
                    + bflo(a.y) * b0.z + bfhi(a.y) * b0.w
                    + bflo(a.z) * b1.x + bfhi(a.z) * b1.y
                    + bflo(a.w) * b1.z + bfhi(a.w) * b1.w;
            uint4 a2 = wh[c];
            float4 c0 = hv[2 * c], c1 = hv[2 * c + 1];
            acc[3 + g] += bflo(a2.x) * c0.x + bfhi(a2.x) * c0.y
                        + bflo(a2.y) * c0.z + bfhi(a2.y) * c0.w
                        + bflo(a2.z) * c1.x + bfhi(a2.z) * c1.y
                        + bflo(a2.w) * c1.z + bfhi(a2.w) * c1.w;
        }
    }
    __shared__ float sred[6][4];
    int wid = threadIdx.x >> 6, lane = threadIdx.x & 63;
#pragma unroll
    for (int g = 0; g < 6; ++g) {
        float r = wave_reduce(acc[g]);
        if (lane == 0) sred[g][wid] = r;
    }
    __syncthreads();
    if (threadIdx.x == 0) {
        float ir  = sred[0][0] + sred[0][1] + sred[0][2] + sred[0][3];
        float iz  = sred[1][0] + sred[1][1] + sred[1][2] + sred[1][3];
        float in_ = sred[2][0] + sred[2][1] + sred[2][2] + sred[2][3];
        float hr  = sred[3][0] + sred[3][1] + sred[3][2] + sred[3][3];
        float hz  = sred[4][0] + sred[4][1] + sred[4][2] + sred[4][3];
        float hn  = sred[5][0] + sred[5][1] + sred[5][2] + sred[5][3];
        float r = 1.f / (1.f + expf(-(ir + hr)));
        float z = 1.f / (1.f + expf(-(iz + hz)));
        float n = tanhf(in_ + r * hn);
        h_out[t] = (1.f - z) * n + z * h[t];
        if (t < 3) logits3[t] = 0.f;
    }
}

// ---------------------------------------------------------------------------
// logits3[l] += sum_f W3[f][l] * feat[f], feat built on the fly from
// (sk_new, xk).  grid = 64 blocks x 256 threads = exactly NF threads.
// ---------------------------------------------------------------------------
__global__ void feat_kernel(const float* __restrict__ W3,
                            const float* __restrict__ s,
                            const float* __restrict__ x,
                            float* __restrict__ logits3) {
    int f = blockIdx.x * blockDim.x + threadIdx.x;   // 0..16383
    int j = f & (N - 1);
    int seg = f >> 12;
    float sv = s[j], xv = x[j];
    float val;
    if (seg == 0)      val = sv;
    else if (seg == 1) val = xv;
    else if (seg == 2) val = fabsf(sv - xv);
    else               val = sv * xv;
    float l0 = val * W3[f * 3 + 0];
    float l1 = val * W3[f * 3 + 1];
    float l2 = val * W3[f * 3 + 2];

    __shared__ float red[3][256];
    red[0][threadIdx.x] = l0;
    red[1][threadIdx.x] = l1;
    red[2][threadIdx.x] = l2;
    __syncthreads();
    for (int st = 128; st > 0; st >>= 1) {
        if (threadIdx.x < st)
            for (int g = 0; g < 3; ++g)
                red[g][threadIdx.x] += red[g][threadIdx.x + st];
        __syncthreads();
    }
    if (threadIdx.x == 0) {
        atomicAdd(&logits3[0], red[0][0]);
        atomicAdd(&logits3[1], red[1][0]);
        atomicAdd(&logits3[2], red[2][0]);
    }
}

// ---------------------------------------------------------------------------
// P_r += softmax(logits3); on the final step write out = P_r / K.
// ---------------------------------------------------------------------------
__global__ void acc3_kernel(const float* __restrict__ l3,
                            float* __restrict__ Pr,
                            float* __restrict__ out,
                            int finalize) {
    if (threadIdx.x == 0 && blockIdx.x == 0) {
        float a = l3[0], b = l3[1], c = l3[2];
        float m = fmaxf(a, fmaxf(b, c));
        float e0 = expf(a - m), e1 = expf(b - m), e2 = expf(c - m);
        float s = e0 + e1 + e2;
        float p0 = Pr[0] + e0 / s;
        float p1 = Pr[1] + e1 / s;
        float p2 = Pr[2] + e2 / s;
        Pr[0] = p0; Pr[1] = p1; Pr[2] = p2;
        if (finalize) {
            out[0] = p0 / (float)KSTEPS;
            out[1] = p1 / (float)KSTEPS;
            out[2] = p2 / (float)KSTEPS;
        }
    }
}

extern "C" void kernel_launch(void* const* d_in, const int* in_sizes, int n_in,
                              void* d_out, int out_size, void* d_ws, size_t ws_size,
                              hipStream_t stream) {
    const float* M_h  = (const float*)d_in[0];
    const float* M_p  = (const float*)d_in[1];
    const float* w1   = (const float*)d_in[2];
    const float* W2   = (const float*)d_in[3];
    const float* W3   = (const float*)d_in[4];
    const float* w_ih = (const float*)d_in[5];
    const float* w_hh = (const float*)d_in[6];
    float* out = (float*)d_out;

    float* ws    = (float*)d_ws;
    float* buf_v = ws;            // 4096  logits scratch (v, beta-logits)
    float* buf_w = ws + 4096;     // 4096  softmax weights (alpha / beta)
    float* sk_a  = ws + 8192;     // 4096  hidden state ping
    float* sk_b  = ws + 12288;    // 4096  hidden state pong
    float* xk    = ws + 16384;    // 4096  GRU input vector
    float* u     = ws + 20480;    // 4096  W2 @ sk
    float* l3    = ws + 24576;    // 3     label logits
    float* Pr    = ws + 24579;    // 3     accumulated probabilities

    // bf16 mirrors of the big per-step matrices (256 MiB total; ws is 768 MiB)
    // byte offset 24832*4 = 99328 (16B aligned)
    ushort* bfb  = (ushort*)(ws + 24832);
    ushort* W2b  = bfb;                            // N*N bf16 = 32 MiB
    ushort* Mpb  = W2b  + (size_t)N * N;           // 32 MiB
    ushort* wihb = Mpb  + (size_t)N * N;           // 3*N*N bf16 = 96 MiB
    ushort* whhb = wihb + (size_t)3 * N * N;       // 96 MiB

    // zero the small fp32 scratch region (ws is poisoned to 0xAA)
    hipMemsetAsync(d_ws, 0, (size_t)24592 * sizeof(float), stream);

    // one-time fp32 -> bf16 compression of the per-step weight streams
    convert_bf16_kernel<<<2048, 256, 0, stream>>>(W2,   (uint4*)W2b,  N * N / 8);
    convert_bf16_kernel<<<2048, 256, 0, stream>>>(M_p,  (uint4*)Mpb,  N * N / 8);
    convert_bf16_kernel<<<2048, 256, 0, stream>>>(w_ih, (uint4*)wihb, 3 * N * N / 8);
    convert_bf16_kernel<<<2048, 256, 0, stream>>>(w_hh, (uint4*)whhb, 3 * N * N / 8);

    dim3 csGrid(4, 128);

    // alpha = softmax(w1^T M_h);  sk0 = alpha @ M_h   (fp32 path, runs once)
    colsum_kernel<<<csGrid, 256, 0, stream>>>(M_h, w1, buf_v, 32);
    softmax_kernel<<<1, 1024, 0, stream>>>(buf_v, buf_w, nullptr);
    colsum_kernel<<<csGrid, 256, 0, stream>>>(M_h, buf_w, sk_a, 32);

    dim3 csbGrid(2, 256);

    float* h  = sk_a;
    float* hn = sk_b;
    for (int k = 0; k < KSTEPS; ++k) {
        // beta-logits = (W2 @ h)^T @ M_p   (no 4096^3 GEMM needed)
        rowdot_u_bf16_kernel<<<4096, 256, 0, stream>>>(W2b, h, u, buf_v);
        colsum_bf16_kernel<<<csbGrid, 256, 0, stream>>>(Mpb, u, buf_v, 16);
        softmax_kernel<<<1, 1024, 0, stream>>>(buf_v, buf_w, xk); // beta; zero xk
        // xk = beta @ M_p
        colsum_bf16_kernel<<<csbGrid, 256, 0, stream>>>(Mpb, buf_w, xk, 16);
        // h' = GRUCell(xk, h)
        gru_bf16_kernel<<<4096, 256, 0, stream>>>(wihb, whhb, xk, h, hn, l3);
        // P_r += softmax(W3^T feat(h', xk))
        feat_kernel<<<64, 256, 0, stream>>>(W3, hn, xk, l3);
        acc3_kernel<<<1, 64, 0, stream>>>(l3, Pr, out, k == KSTEPS - 1 ? 1 : 0);
        float* t = h; h = hn; hn = t;
    }
}

// Round 2
// 1949.687 us; speedup vs baseline: 1.0127x; 1.0127x over previous
//
#include <hip/hip_runtime.h>
#include <math.h>

// Problem constants (fixed by the reference)
#define N      4096          // N_HID == N_TH == N_TP
#define N8     (N / 8)       // 512 groups of 8 bf16 (one uint4) per row
#define KSTEPS 8
#define NF     16384         // feature length for W3 (nH + nP + 2*maxL)

// ---------------------------------------------------------------------------
// bf16 helpers: weights are stored as packed bf16 (2 per uint32), vectors and
// accumulation stay fp32.  bflo/bfhi unpack the low/high bf16 of a uint32.
// ---------------------------------------------------------------------------
__device__ __forceinline__ float bflo(uint32_t u) { return __uint_as_float(u << 16); }
__device__ __forceinline__ float bfhi(uint32_t u) { return __uint_as_float(u & 0xffff0000u); }
__device__ __forceinline__ uint32_t f2bf(float f) {
    // round-to-nearest-even fp32 -> bf16 (inputs are finite normals)
    uint32_t u = __float_as_uint(f);
    return (u + 0x7fffu + ((u >> 16) & 1u)) >> 16;
}
__device__ __forceinline__ float wave_reduce(float v) {
#pragma unroll
    for (int off = 32; off > 0; off >>= 1) v += __shfl_down(v, off, 64);
    return v;
}
// dot of 8 packed bf16 (one uint4) with 8 fp32 (two float4)
__device__ __forceinline__ float dot8(uint4 a, float4 b0, float4 b1) {
    return bflo(a.x) * b0.x + bfhi(a.x) * b0.y
         + bflo(a.y) * b0.z + bfhi(a.y) * b0.w
         + bflo(a.z) * b1.x + bfhi(a.z) * b1.y
         + bflo(a.w) * b1.z + bfhi(a.w) * b1.w;
}

// ---------------------------------------------------------------------------
// fp32 -> packed bf16 conversion, 8 elements (32B read, 16B write) per iter.
// ---------------------------------------------------------------------------
__global__ void convert_bf16_kernel(const float* __restrict__ src,
                                    uint4* __restrict__ dst, int n8) {
    int i = blockIdx.x * blockDim.x + threadIdx.x;
    int stride = gridDim.x * blockDim.x;
    const float4* s = (const float4*)src;
    for (; i < n8; i += stride) {
        float4 a = s[2 * (size_t)i];
        float4 b = s[2 * (size_t)i + 1];
        uint4 o;
        o.x = f2bf(a.x) | (f2bf(a.y) << 16);
        o.y = f2bf(a.z) | (f2bf(a.w) << 16);
        o.z = f2bf(b.x) | (f2bf(b.y) << 16);
        o.w = f2bf(b.z) | (f2bf(b.w) << 16);
        dst[i] = o;
    }
}

// ---------------------------------------------------------------------------
// fp32 weighted column sum (used only for the M_h init path):
// out[j] += sum_{i in slice} w[i] * M[i][j].  out must be pre-zeroed.
// ---------------------------------------------------------------------------
__global__ void colsum_kernel(const float* __restrict__ M,
                              const float* __restrict__ w,
                              float* __restrict__ out,
                              int rowsPerSlice) {
    int c4 = blockIdx.x * blockDim.x + threadIdx.x;      // float4 column idx
    int i0 = blockIdx.y * rowsPerSlice;
    float4 acc = make_float4(0.f, 0.f, 0.f, 0.f);
    for (int i = i0; i < i0 + rowsPerSlice; ++i) {
        float wi = w[i];
        float4 m = ((const float4*)(M + (size_t)i * N))[c4];
        acc.x += wi * m.x;
        acc.y += wi * m.y;
        acc.z += wi * m.z;
        acc.w += wi * m.w;
    }
    atomicAdd(&out[c4 * 4 + 0], acc.x);
    atomicAdd(&out[c4 * 4 + 1], acc.y);
    atomicAdd(&out[c4 * 4 + 2], acc.z);
    atomicAdd(&out[c4 * 4 + 3], acc.w);
}

// ---------------------------------------------------------------------------
// bf16 weighted column sum: out[j] += sum_{i in slice} w[i] * Mb[i][j].
// Each thread owns 8 consecutive columns (one uint4 = 8 bf16).
// grid = (2, 256), block = 256, rowsPerSlice = 16.
// launch_bounds(256,8): VGPR<=64 -> 32 waves/CU (kernel is ~30 VGPR).
// ---------------------------------------------------------------------------
__global__ __launch_bounds__(256, 8)
void colsum_bf16_kernel(const ushort* __restrict__ Mb,
                        const float* __restrict__ w,
                        float* __restrict__ out,
                        int rowsPerSlice) {
    int c8 = blockIdx.x * blockDim.x + threadIdx.x;      // [0, 512)
    int i0 = blockIdx.y * rowsPerSlice;
    float a0 = 0.f, a1 = 0.f, a2 = 0.f, a3 = 0.f;
    float a4 = 0.f, a5 = 0.f, a6 = 0.f, a7 = 0.f;
    for (int i = i0; i < i0 + rowsPerSlice; ++i) {
        float wi = w[i];
        uint4 m = ((const uint4*)(Mb + (size_t)i * N))[c8];
        a0 += wi * bflo(m.x); a1 += wi * bfhi(m.x);
        a2 += wi * bflo(m.y); a3 += wi * bfhi(m.y);
        a4 += wi * bflo(m.z); a5 += wi * bfhi(m.z);
        a6 += wi * bflo(m.w); a7 += wi * bfhi(m.w);
    }
    float* o = out + c8 * 8;
    atomicAdd(o + 0, a0); atomicAdd(o + 1, a1);
    atomicAdd(o + 2, a2); atomicAdd(o + 3, a3);
    atomicAdd(o + 4, a4); atomicAdd(o + 5, a5);
    atomicAdd(o + 6, a6); atomicAdd(o + 7, a7);
}

// ---------------------------------------------------------------------------
// u[row] = dot(W2b[row, :], sk)  (bf16 weights, fp32 vector/accum).
// One block (256 thr) per row; wave-shuffle reduction.
// Also zeroes bufv[row] for the following colsum.
// ---------------------------------------------------------------------------
__global__ __launch_bounds__(256, 8)
void rowdot_u_bf16_kernel(const ushort* __restrict__ W2b,
                          const float* __restrict__ sk,
                          float* __restrict__ u,
                          float* __restrict__ bufv) {
    int row = blockIdx.x;
    const uint4* r = (const uint4*)(W2b + (size_t)row * N);
    const float4* x = (const float4*)sk;
    float acc = 0.f;
    for (int c = threadIdx.x; c < N8; c += blockDim.x) {
        uint4 a = r[c];
        float4 b0 = x[2 * c], b1 = x[2 * c + 1];
        acc += dot8(a, b0, b1);
    }
    acc = wave_reduce(acc);
    __shared__ float s4[4];
    if ((threadIdx.x & 63) == 0) s4[threadIdx.x >> 6] = acc;
    __syncthreads();
    if (threadIdx.x == 0) {
        u[row]    = s4[0] + s4[1] + s4[2] + s4[3];
        bufv[row] = 0.f;     // pre-zero logits buffer for the next colsum
    }
}

// ---------------------------------------------------------------------------
// Single-block softmax over N entries: wgt = softmax(v).
// Optionally zeroes zbuf[0..N) (the xk accumulator for the next colsum).
// ---------------------------------------------------------------------------
__global__ void softmax_kernel(const float* __restrict__ v,
                               float* __restrict__ wgt,
                               float* __restrict__ zbuf) {
    __shared__ float red[1024];
    int tid = threadIdx.x;
    float m = -1e30f;
    for (int i = tid; i < N; i += 1024) m = fmaxf(m, v[i]);
    red[tid] = m;
    __syncthreads();
    for (int s = 512; s > 0; s >>= 1) {
        if (tid < s) red[tid] = fmaxf(red[tid], red[tid + s]);
        __syncthreads();
    }
    float mx = red[0];
    __syncthreads();
    float sum = 0.f;
    for (int i = tid; i < N; i += 1024) {
        float e = expf(v[i] - mx);
        wgt[i] = e;
        sum += e;
    }
    red[tid] = sum;
    __syncthreads();
    for (int s = 512; s > 0; s >>= 1) {
        if (tid < s) red[tid] += red[tid + s];
        __syncthreads();
    }
    float inv = 1.f / red[0];
    for (int i = tid; i < N; i += 1024) wgt[i] *= inv;
    if (zbuf) {
        for (int i = tid; i < N; i += 1024) zbuf[i] = 0.f;
    }
}

// ---------------------------------------------------------------------------
// Fused GRU cell with bf16 weights: one block per hidden unit t.
// c-outer / gate-inner: the 6 weight streams share one x/h load; explicit
// distinct load registers bound the live set (~55 VGPR).
// launch_bounds(256,6): VGPR<=85 -> >=24 waves/CU, no spill risk.
// Blocks 0..2 also zero logits3 for the following feat reduction.
// ---------------------------------------------------------------------------
__global__ __launch_bounds__(256, 6)
void gru_bf16_kernel(const ushort* __restrict__ wihb,
                     const ushort* __restrict__ whhb,
                     const float* __restrict__ xk,
                     const float* __restrict__ h,
                     float* __restrict__ h_out,
                     float* __restrict__ logits3) {
    int t = blockIdx.x;
    const float4* xv = (const float4*)xk;
    const float4* hv = (const float4*)h;
    const uint4* wi0 = (const uint4*)(wihb + (size_t)(0 * N + t) * N);
    const uint4* wi1 = (const uint4*)(wihb + (size_t)(1 * N + t) * N);
    const uint4* wi2 = (const uint4*)(wihb + (size_t)(2 * N + t) * N);
    const uint4* wh0 = (const uint4*)(whhb + (size_t)(0 * N + t) * N);
    const uint4* wh1 = (const uint4*)(whhb + (size_t)(1 * N + t) * N);
    const uint4* wh2 = (const uint4*)(whhb + (size_t)(2 * N + t) * N);
    float acc0 = 0.f, acc1 = 0.f, acc2 = 0.f;
    float acc3 = 0.f, acc4 = 0.f, acc5 = 0.f;
    for (int c = threadIdx.x; c < N8; c += blockDim.x) {
        uint4 A0 = wi0[c], A1 = wi1[c], A2 = wi2[c];
        uint4 B0 = wh0[c], B1 = wh1[c], B2 = wh2[c];
        float4 b0 = xv[2 * c], b1 = xv[2 * c + 1];
        float4 d0 = hv[2 * c], d1 = hv[2 * c + 1];
        acc0 += dot8(A0, b0, b1);
        acc1 += dot8(A1, b0, b1);
        acc2 += dot8(A2, b0, b1);
        acc3 += dot8(B0, d0, d1);
        acc4 += dot8(B1, d0, d1);
        acc5 += dot8(B2, d0, d1);
    }
    __shared__ float sred[6][4];
    int wid = threadIdx.x >> 6, lane = threadIdx.x & 63;
    float r0 = wave_reduce(acc0);
    float r1 = wave_reduce(acc1);
    float r2 = wave_reduce(acc2);
    float r3 = wave_reduce(acc3);
    float r4 = wave_reduce(acc4);
    float r5 = wave_reduce(acc5);
    if (lane == 0) {
        sred[0][wid] = r0; sred[1][wid] = r1; sred[2][wid] = r2;
        sred[3][wid] = r3; sred[4][wid] = r4; sred[5][wid] = r5;
    }
    __syncthreads();
    if (threadIdx.x == 0) {
        float ir  = sred[0][0] + sred[0][1] + sred[0][2] + sred[0][3];
        float iz  = sred[1][0] + sred[1][1] + sred[1][2] + sred[1][3];
        float in_ = sred[2][0] + sred[2][1] + sred[2][2] + sred[2][3];
        float hr  = sred[3][0] + sred[3][1] + sred[3][2] + sred[3][3];
        float hz  = sred[4][0] + sred[4][1] + sred[4][2] + sred[4][3];
        float hn  = sred[5][0] + sred[5][1] + sred[5][2] + sred[5][3];
        float r = 1.f / (1.f + expf(-(ir + hr)));
        float z = 1.f / (1.f + expf(-(iz + hz)));
        float n = tanhf(in_ + r * hn);
        h_out[t] = (1.f - z) * n + z * h[t];
        if (t < 3) logits3[t] = 0.f;
    }
}

// ---------------------------------------------------------------------------
// logits3[l] += sum_f W3[f][l] * feat[f], feat built on the fly from
// (sk_new, xk).  grid = 64 blocks x 256 threads = exactly NF threads.
// ---------------------------------------------------------------------------
__global__ void feat_kernel(const float* __restrict__ W3,
                            const float* __restrict__ s,
                            const float* __restrict__ x,
                            float* __restrict__ logits3) {
    int f = blockIdx.x * blockDim.x + threadIdx.x;   // 0..16383
    int j = f & (N - 1);
    int seg = f >> 12;
    float sv = s[j], xv = x[j];
    float val;
    if (seg == 0)      val = sv;
    else if (seg == 1) val = xv;
    else if (seg == 2) val = fabsf(sv - xv);
    else               val = sv * xv;
    float l0 = val * W3[f * 3 + 0];
    float l1 = val * W3[f * 3 + 1];
    float l2 = val * W3[f * 3 + 2];

    __shared__ float red[3][256];
    red[0][threadIdx.x] = l0;
    red[1][threadIdx.x] = l1;
    red[2][threadIdx.x] = l2;
    __syncthreads();
    for (int st = 128; st > 0; st >>= 1) {
        if (threadIdx.x < st)
            for (int g = 0; g < 3; ++g)
                red[g][threadIdx.x] += red[g][threadIdx.x + st];
        __syncthreads();
    }
    if (threadIdx.x == 0) {
        atomicAdd(&logits3[0], red[0][0]);
        atomicAdd(&logits3[1], red[1][0]);
        atomicAdd(&logits3[2], red[2][0]);
    }
}

// ---------------------------------------------------------------------------
// P_r += softmax(logits3); on the final step write out = P_r / K.
// ---------------------------------------------------------------------------
__global__ void acc3_kernel(const float* __restrict__ l3,
                            float* __restrict__ Pr,
                            float* __restrict__ out,
                            int finalize) {
    if (threadIdx.x == 0 && blockIdx.x == 0) {
        float a = l3[0], b = l3[1], c = l3[2];
        float m = fmaxf(a, fmaxf(b, c));
        float e0 = expf(a - m), e1 = expf(b - m), e2 = expf(c - m);
        float s = e0 + e1 + e2;
        float p0 = Pr[0] + e0 / s;
        float p1 = Pr[1] + e1 / s;
        float p2 = Pr[2] + e2 / s;
        Pr[0] = p0; Pr[1] = p1; Pr[2] = p2;
        if (finalize) {
            out[0] = p0 / (float)KSTEPS;
            out[1] = p1 / (float)KSTEPS;
            out[2] = p2 / (float)KSTEPS;
        }
    }
}

extern "C" void kernel_launch(void* const* d_in, const int* in_sizes, int n_in,
                              void* d_out, int out_size, void* d_ws, size_t ws_size,
                              hipStream_t stream) {
    const float* M_h  = (const float*)d_in[0];
    const float* M_p  = (const float*)d_in[1];
    const float* w1   = (const float*)d_in[2];
    const float* W2   = (const float*)d_in[3];
    const float* W3   = (const float*)d_in[4];
    const float* w_ih = (const float*)d_in[5];
    const float* w_hh = (const float*)d_in[6];
    float* out = (float*)d_out;

    float* ws    = (float*)d_ws;
    float* buf_v = ws;            // 4096  logits scratch (v, beta-logits)
    float* buf_w = ws + 4096;     // 4096  softmax weights (alpha / beta)
    float* sk_a  = ws + 8192;     // 4096  hidden state ping
    float* sk_b  = ws + 12288;    // 4096  hidden state pong
    float* xk    = ws + 16384;    // 4096  GRU input vector
    float* u     = ws + 20480;    // 4096  W2 @ sk
    float* l3    = ws + 24576;    // 3     label logits
    float* Pr    = ws + 24579;    // 3     accumulated probabilities

    // bf16 mirrors of the big per-step matrices (256 MiB total; ws is 768 MiB)
    // byte offset 24832*4 = 99328 (16B aligned)
    ushort* bfb  = (ushort*)(ws + 24832);
    ushort* W2b  = bfb;                            // N*N bf16 = 32 MiB
    ushort* Mpb  = W2b  + (size_t)N * N;           // 32 MiB
    ushort* wihb = Mpb  + (size_t)N * N;           // 3*N*N bf16 = 96 MiB
    ushort* whhb = wihb + (size_t)3 * N * N;       // 96 MiB

    // zero the small fp32 scratch region (ws is poisoned to 0xAA)
    hipMemsetAsync(d_ws, 0, (size_t)24592 * sizeof(float), stream);

    // one-time fp32 -> bf16 compression of the per-step weight streams
    convert_bf16_kernel<<<2048, 256, 0, stream>>>(W2,   (uint4*)W2b,  N * N / 8);
    convert_bf16_kernel<<<2048, 256, 0, stream>>>(M_p,  (uint4*)Mpb,  N * N / 8);
    convert_bf16_kernel<<<2048, 256, 0, stream>>>(w_ih, (uint4*)wihb, 3 * N * N / 8);
    convert_bf16_kernel<<<2048, 256, 0, stream>>>(w_hh, (uint4*)whhb, 3 * N * N / 8);

    dim3 csGrid(4, 128);

    // alpha = softmax(w1^T M_h);  sk0 = alpha @ M_h   (fp32 path, runs once)
    colsum_kernel<<<csGrid, 256, 0, stream>>>(M_h, w1, buf_v, 32);
    softmax_kernel<<<1, 1024, 0, stream>>>(buf_v, buf_w, nullptr);
    colsum_kernel<<<csGrid, 256, 0, stream>>>(M_h, buf_w, sk_a, 32);

    dim3 csbGrid(2, 256);

    float* h  = sk_a;
    float* hn = sk_b;
    for (int k = 0; k < KSTEPS; ++k) {
        // beta-logits = (W2 @ h)^T @ M_p   (no 4096^3 GEMM needed)
        rowdot_u_bf16_kernel<<<4096, 256, 0, stream>>>(W2b, h, u, buf_v);
        colsum_bf16_kernel<<<csbGrid, 256, 0, stream>>>(Mpb, u, buf_v, 16);
        softmax_kernel<<<1, 1024, 0, stream>>>(buf_v, buf_w, xk); // beta; zero xk
        // xk = beta @ M_p
        colsum_bf16_kernel<<<csbGrid, 256, 0, stream>>>(Mpb, buf_w, xk, 16);
        // h' = GRUCell(xk, h)
        gru_bf16_kernel<<<4096, 256, 0, stream>>>(wihb, whhb, xk, h, hn, l3);
        // P_r += softmax(W3^T feat(h', xk))
        feat_kernel<<<64, 256, 0, stream>>>(W3, hn, xk, l3);
        acc3_kernel<<<1, 64, 0, stream>>>(l3, Pr, out, k == KSTEPS - 1 ? 1 : 0);
        float* t = h; h = hn; hn = t;
    }
}